// Round 7
// baseline (23034.914 us; speedup 1.0000x reference)
//
#include <hip/hip_runtime.h>
#include <hip/hip_fp16.h>

#define BB 8
#define SS 2048
#define EE 1024
#define NHH 4
#define DHH 256

typedef _Float16 f16x2 __attribute__((ext_vector_type(2)));

__device__ __forceinline__ __half2 u2h2(unsigned int u) {
  union { unsigned int u; __half2 h; } c; c.u = u; return c.h;
}
__device__ __forceinline__ unsigned int h2u(__half2 h) {
  union { unsigned int u; __half2 h; } c; c.h = h; return c.u;
}
__device__ __forceinline__ f16x2 u2f(unsigned int u) {
  union { unsigned int u; f16x2 f; } c; c.u = u; return c.f;
}
__device__ __forceinline__ unsigned int pack2(float a, float b) {
  f16x2 f; f.x = (_Float16)a; f.y = (_Float16)b;
  union { f16x2 f; unsigned int u; } c; c.f = f; return c.u;
}
__device__ __forceinline__ float fdot2u(unsigned int w, unsigned int y, float acc) {
#if __has_builtin(__builtin_amdgcn_fdot2)
  return __builtin_amdgcn_fdot2(u2f(w), u2f(y), acc, false);
#else
  __half2 a = u2h2(w), b = u2h2(y);
  return acc + __low2float(a) * __low2float(b) + __high2float(a) * __high2float(b);
#endif
}

// ---------------------------------------------------------------------------
// Gates projection GEMM (unchanged from round 5/6).
// Output: gx f16, layout [S][B][NH][4*DH] = [i(256) f(256) z(256) o(256)]
// ---------------------------------------------------------------------------
__global__ __launch_bounds__(256) void gates_gemm(
    const float* __restrict__ x, const float* __restrict__ conv_w,
    const float* __restrict__ conv_b,
    const float* __restrict__ fgw, const float* __restrict__ igw,
    const float* __restrict__ zgw, const float* __restrict__ ogw,
    __half* __restrict__ gx)
{
  __shared__ float Xs[67][33];
  __shared__ float As[64][33];
  __shared__ float Bs[32][68];

  const int tid = threadIdx.x;
  const int mt = blockIdx.x;
  const int nt = blockIdx.y;
  const int p  = blockIdx.z;
  const int h  = p >> 1, pair = p & 1;
  const int b  = mt >> 5;
  const int s0 = (mt & 31) << 6;
  const int n0 = nt << 6;

  const float* W0 = pair ? zgw : fgw;
  const float* W1 = pair ? ogw : igw;

  const int tx = tid & 15, ty = tid >> 4;
  float acc[4][4] = {};

  for (int d0 = 0; d0 < DHH; d0 += 32) {
    for (int i = tid; i < 67 * 32; i += 256) {
      int r = i >> 5, c = i & 31;
      int s = s0 - 3 + r;
      float v = 0.f;
      if (s >= 0) v = x[((size_t)b * SS + s) * EE + h * DHH + d0 + c];
      Xs[r][c] = v;
    }
    for (int i = tid; i < 32 * 64; i += 256) {
      int j = i >> 5, c = i & 31;
      int o = n0 + j;
      const float* Wp = (o < 256) ? W0 : W1;
      int oo = o & 255;
      Bs[c][j] = Wp[((size_t)h * DHH + oo) * DHH + d0 + c];
    }
    __syncthreads();
    if (pair == 0) {
      for (int i = tid; i < 64 * 32; i += 256) {
        int r = i >> 5, c = i & 31;
        int e = h * DHH + d0 + c;
        float xc = conv_b[e];
        xc = fmaf(Xs[r + 0][c], conv_w[0 * EE + e], xc);
        xc = fmaf(Xs[r + 1][c], conv_w[1 * EE + e], xc);
        xc = fmaf(Xs[r + 2][c], conv_w[2 * EE + e], xc);
        xc = fmaf(Xs[r + 3][c], conv_w[3 * EE + e], xc);
        float sg = 1.f / (1.f + __expf(-xc));
        As[r][c] = xc * sg;
      }
    } else {
      for (int i = tid; i < 64 * 32; i += 256) {
        int r = i >> 5, c = i & 31;
        As[r][c] = Xs[r + 3][c];
      }
    }
    __syncthreads();
#pragma unroll
    for (int kk = 0; kk < 32; ++kk) {
      float a[4];
#pragma unroll
      for (int i = 0; i < 4; ++i) a[i] = As[ty * 4 + i][kk];
      float4 bv = *(const float4*)&Bs[kk][tx * 4];
      float bb[4] = {bv.x, bv.y, bv.z, bv.w};
#pragma unroll
      for (int i = 0; i < 4; ++i)
#pragma unroll
        for (int j = 0; j < 4; ++j)
          acc[i][j] = fmaf(a[i], bb[j], acc[i][j]);
    }
    __syncthreads();
  }

#pragma unroll
  for (int i = 0; i < 4; ++i) {
    int s = s0 + ty * 4 + i;
    size_t base = (((size_t)s * BB + b) * NHH + h) * 1024 + (size_t)pair * 512 + n0 + tx * 4;
    uint2 st;
    st.x = h2u(__floats2half2_rn(acc[i][0], acc[i][1]));
    st.y = h2u(__floats2half2_rn(acc[i][2], acc[i][3]));
    *(uint2*)(gx + base) = st;
  }
}

// ---------------------------------------------------------------------------
// sLSTM scan, 2 CUs per chain. grid = 64 WGs x 1024 threads.
//   blockIdx: myhalf = bid>>5 (dims [myhalf*128, myhalf*128+128)), c = bid&31.
// Lane map: wave w = t>>6, lane l = t&63.
//   p = w&1 (k-half consumed), g = l&3 (gate), d_loc = (w>>1)*16 + (l>>2).
//   col = g*256 + myhalf*128 + d_loc; weights = 64 half2 (k in [p*128,p*128+128)).
// Per step: 64 fdot2 over y-half (own half from LDS ystage, peer half from
// global ring after acquire-spin on stamp); k-half combine via LDS partial
// (wave w <-> w^1); gate gather via shfl_xor(1),(2); state redundant x8.
// t0 publishes own y-half (16 dwordx4 + release stamp) into ring of 4 slots.
// Skew between the two WGs of a chain is <=1 step -> ring-4 is safe.
// Dynamic LDS 98304 B forces 1 WG/CU.
// ---------------------------------------------------------------------------
__global__ __attribute__((amdgpu_flat_work_group_size(1024, 1024)))
void slstm_scan2(
    const float* __restrict__ rk,    // (NH, DH, 4*DH)
    const float* __restrict__ rb,    // (NH, 4, DH)
    const __half* __restrict__ gx,   // [S][B][NH][1024]
    float* __restrict__ out,         // (B, S, E)
    __half* __restrict__ ybuf,       // [32][2][4][128] f16 ring
    int* __restrict__ yflag)         // [32][2][4] stamps (memset 0 per launch)
{
  extern __shared__ unsigned char smem2[];
  float* partial = (float*)smem2;                                // [2][1024]
  __half (*ystage)[128] = (__half(*)[128])(smem2 + 8192);        // [4][128]
  float (*ostage)[128] = (float(*)[128])(smem2 + 8192 + 1024);   // [4][128]

  const int t = threadIdx.x;
  const int w = t >> 6, l = t & 63;
  const int myhalf = blockIdx.x >> 5;
  const int c = blockIdx.x & 31;
  const int b = c >> 2, h = c & 3;
  const int p = w & 1;
  const int g = l & 3;
  const int d_loc = ((w >> 1) << 4) | (l >> 2);       // 0..127
  const int col = g * 256 + myhalf * 128 + d_loc;     // 0..1023
  const float* Rh = rk + (size_t)h * DHH * 1024;

  // 64 half2 weights: k in [p*128, p*128+128), fully register-resident
  unsigned int wv[64];
#pragma unroll
  for (int i = 0; i < 64; ++i) {
    int k = (p << 7) + 2 * i;
    wv[i] = pack2(Rh[(size_t)k * 1024 + col], Rh[(size_t)(k + 1) * 1024 + col]);
  }
  const float rbv = rb[h * 1024 + col];

  // prologue: zero y(0) staging + publish zero slot 0
  if (t < 128) {
#pragma unroll
    for (int s = 0; s < 4; ++s) ystage[s][t] = __float2half(0.f);
  }
  if (t == 0) {
    uint4 z; z.x = z.y = z.z = z.w = 0u;
    uint4* dst = (uint4*)(ybuf + (((size_t)c * 2 + myhalf) * 4 + 0) * 128);
#pragma unroll
    for (int j = 0; j < 16; ++j) dst[j] = z;
    __hip_atomic_store(&yflag[(c * 2 + myhalf) * 4 + 0], 1,
                       __ATOMIC_RELEASE, __HIP_MEMORY_SCOPE_AGENT);
  }
  __syncthreads();

  float cst = 0.f, nst = 0.f, mst = 0.f;
  const size_t gxstep = (size_t)BB * NHH * 1024;
  const __half* gp = gx + ((size_t)b * NHH + h) * 1024 + col;

  for (int st = 0; st < SS; ++st) {
    const int slot = st & 3;
    // issue this step's gate-input load early (independent of y)
    const float cx = __half2float(gp[(size_t)st * gxstep]);

    // ---- matvec over this lane's k-half ----
    float dotsum = 0.f;
    if (p == myhalf) {
      const uint4* ys = (const uint4*)ystage[slot];
#pragma unroll
      for (int j = 0; j < 16; ++j) {
        uint4 yq = ys[j];
        dotsum = fdot2u(wv[4 * j + 0], yq.x, dotsum);
        dotsum = fdot2u(wv[4 * j + 1], yq.y, dotsum);
        dotsum = fdot2u(wv[4 * j + 2], yq.z, dotsum);
        dotsum = fdot2u(wv[4 * j + 3], yq.w, dotsum);
      }
    } else {
      const int fidx = (c * 2 + p) * 4 + slot;
      const int want = st + 1;
      while (__hip_atomic_load(&yflag[fidx], __ATOMIC_ACQUIRE,
                               __HIP_MEMORY_SCOPE_AGENT) < want) {
        __builtin_amdgcn_s_sleep(2);
      }
      const uint4* ys = (const uint4*)(ybuf + (((size_t)c * 2 + p) * 4 + slot) * 128);
#pragma unroll
      for (int j = 0; j < 16; ++j) {
        uint4 yq = ys[j];
        dotsum = fdot2u(wv[4 * j + 0], yq.x, dotsum);
        dotsum = fdot2u(wv[4 * j + 1], yq.y, dotsum);
        dotsum = fdot2u(wv[4 * j + 2], yq.z, dotsum);
        dotsum = fdot2u(wv[4 * j + 3], yq.w, dotsum);
      }
    }

    // ---- combine k-halves across wave pair (w <-> w^1) via LDS ----
    float* pb = partial + (st & 1) * 1024;
    pb[t] = dotsum;
    __syncthreads();                       // b1
    float sum2 = dotsum + pb[t ^ 64];
    float v0 = sum2 + cx + rbv;            // complete raw gate g

    // ---- gather all 4 gates within the 4-lane group ----
    float x1 = __shfl_xor(v0, 1);
    float x2 = __shfl_xor(v0, 2);
    float x3 = __shfl_xor(x1, 2);
    float iv = (g == 0) ? v0 : (g == 1) ? x1 : (g == 2) ? x2 : x3;
    float fv = (g == 0) ? x1 : (g == 1) ? v0 : (g == 2) ? x3 : x2;
    float zv = (g == 0) ? x2 : (g == 1) ? x3 : (g == 2) ? v0 : x1;
    float ov = (g == 0) ? x3 : (g == 1) ? x2 : (g == 2) ? x1 : v0;

    // ---- state update (redundant across the 8 lanes of a dim) ----
    float ea = __expf(-fabsf(fv));
    float ls = fminf(fv, 0.f) - __logf(1.f + ea);      // log_sigmoid(fv)
    float lfm = mst + ls;
    float mn = fmaxf(iv, lfm);
    float ig = __expf(iv - mn);
    float fg = __expf(lfm - mn);
    float pz = __expf(-2.f * fabsf(zv));
    float tmag = __fdividef(1.f - pz, 1.f + pz);
    float th = (zv < 0.f) ? -tmag : tmag;              // tanh(zv)
    cst = fg * cst + ig * th;
    nst = fg * nst + ig;
    float og = __fdividef(1.f, 1.f + __expf(-ov));     // sigmoid(ov)
    float y = og * __fdividef(cst, nst);
    mst = mn;

    // ---- stage y(st+1) and out row ----
    if (((w & 1) == 0) && g == 0) {
      ystage[(st + 1) & 3][d_loc] = __float2half(y);
      ostage[slot][d_loc] = y;
    }
    __syncthreads();                       // b2

    // flush out row (coalesced 512 B)
    if (t < 32) {
      float4 v = *(const float4*)&ostage[slot][t * 4];
      *(float4*)&out[((size_t)b * SS + st) * EE + h * DHH + myhalf * 128 + t * 4] = v;
    }
    // publish own y-half for peer
    if (t == 0 && st + 1 < SS) {
      const int ps = (st + 1) & 3;
      uint4* dst = (uint4*)(ybuf + (((size_t)c * 2 + myhalf) * 4 + ps) * 128);
      const uint4* src = (const uint4*)ystage[ps];
#pragma unroll
      for (int j = 0; j < 16; ++j) dst[j] = src[j];
      __hip_atomic_store(&yflag[(c * 2 + myhalf) * 4 + ps], st + 2,
                         __ATOMIC_RELEASE, __HIP_MEMORY_SCOPE_AGENT);
    }
  }
}

// ---------------------------------------------------------------------------
// GroupNorm over DH per (b,s,h), in place on out. One wave = one head.
// ---------------------------------------------------------------------------
__global__ __launch_bounds__(256) void groupnorm(
    float* __restrict__ y, const float* __restrict__ gnw)
{
  const int row = blockIdx.x;
  const int t = threadIdx.x;
  float4 v = ((const float4*)y)[(size_t)row * 256 + t];
  float s = v.x + v.y + v.z + v.w;
  float q = v.x * v.x + v.y * v.y + v.z * v.z + v.w * v.w;
#pragma unroll
  for (int mask = 1; mask < 64; mask <<= 1) {
    s += __shfl_xor(s, mask, 64);
    q += __shfl_xor(q, mask, 64);
  }
  float mu = s * (1.f / 256.f);
  float var = q * (1.f / 256.f) - mu * mu;
  float rs = rsqrtf(var + 1e-5f);
  float4 g = ((const float4*)gnw)[t];
  float4 o;
  o.x = (v.x - mu) * rs * g.x;
  o.y = (v.y - mu) * rs * g.y;
  o.z = (v.z - mu) * rs * g.z;
  o.w = (v.w - mu) * rs * g.w;
  ((float4*)y)[(size_t)row * 256 + t] = o;
}

extern "C" void kernel_launch(void* const* d_in, const int* in_sizes, int n_in,
                              void* d_out, int out_size, void* d_ws, size_t ws_size,
                              hipStream_t stream) {
  const float* x      = (const float*)d_in[0];
  const float* conv_w = (const float*)d_in[1];
  const float* conv_b = (const float*)d_in[2];
  const float* fgw    = (const float*)d_in[3];
  const float* igw    = (const float*)d_in[4];
  const float* zgw    = (const float*)d_in[5];
  const float* ogw    = (const float*)d_in[6];
  const float* rk     = (const float*)d_in[7];
  const float* rb     = (const float*)d_in[8];
  const float* gnw    = (const float*)d_in[9];
  float* out = (float*)d_out;

  __half* gx   = (__half*)d_ws;                              // 134217728 B
  __half* ybuf = (__half*)((char*)d_ws + 134217728);         // 65536 B
  int*   yflag = (int*)((char*)d_ws + 134217728 + 65536);    // 1024 B

  (void)hipMemsetAsync(yflag, 0, 1024, stream);

  dim3 g1(256, 8, 8);
  gates_gemm<<<g1, 256, 0, stream>>>(x, conv_w, conv_b, fgw, igw, zgw, ogw, gx);

  const int scan_lds = 98304;   // force 1 WG/CU
  (void)hipFuncSetAttribute(reinterpret_cast<const void*>(slstm_scan2),
                            hipFuncAttributeMaxDynamicSharedMemorySize, scan_lds);
  slstm_scan2<<<64, 1024, scan_lds, stream>>>(rk, rb, gx, out, ybuf, yflag);

  groupnorm<<<BB * SS, 256, 0, stream>>>(out, gnw);
}

// Round 9
// 17951.964 us; speedup vs baseline: 1.2831x; 1.2831x over previous
//
#include <hip/hip_runtime.h>
#include <hip/hip_fp16.h>

#define BB 8
#define SS 2048
#define EE 1024
#define NHH 4
#define DHH 256

typedef _Float16 f16x2 __attribute__((ext_vector_type(2)));

__device__ __forceinline__ __half2 u2h2(unsigned int u) {
  union { unsigned int u; __half2 h; } c; c.u = u; return c.h;
}
__device__ __forceinline__ unsigned int h2u(__half2 h) {
  union { unsigned int u; __half2 h; } c; c.h = h; return c.u;
}
__device__ __forceinline__ f16x2 u2f(unsigned int u) {
  union { unsigned int u; f16x2 f; } c; c.u = u; return c.f;
}
__device__ __forceinline__ unsigned int pack2(float a, float b) {
  f16x2 f; f.x = (_Float16)a; f.y = (_Float16)b;
  union { f16x2 f; unsigned int u; } c; c.f = f; return c.u;
}
__device__ __forceinline__ float fdot2u(unsigned int w, unsigned int y, float acc) {
#if __has_builtin(__builtin_amdgcn_fdot2)
  return __builtin_amdgcn_fdot2(u2f(w), u2f(y), acc, false);
#else
  __half2 a = u2h2(w), b = u2h2(y);
  return acc + __low2float(a) * __low2float(b) + __high2float(a) * __high2float(b);
#endif
}

// ---------------------------------------------------------------------------
// Gates projection GEMM (unchanged).
// Output: gx f16, layout [S][B][NH][4*DH] = [i(256) f(256) z(256) o(256)]
// ---------------------------------------------------------------------------
__global__ __launch_bounds__(256) void gates_gemm(
    const float* __restrict__ x, const float* __restrict__ conv_w,
    const float* __restrict__ conv_b,
    const float* __restrict__ fgw, const float* __restrict__ igw,
    const float* __restrict__ zgw, const float* __restrict__ ogw,
    __half* __restrict__ gx)
{
  __shared__ float Xs[67][33];
  __shared__ float As[64][33];
  __shared__ float Bs[32][68];

  const int tid = threadIdx.x;
  const int mt = blockIdx.x;
  const int nt = blockIdx.y;
  const int p  = blockIdx.z;
  const int h  = p >> 1, pair = p & 1;
  const int b  = mt >> 5;
  const int s0 = (mt & 31) << 6;
  const int n0 = nt << 6;

  const float* W0 = pair ? zgw : fgw;
  const float* W1 = pair ? ogw : igw;

  const int tx = tid & 15, ty = tid >> 4;
  float acc[4][4] = {};

  for (int d0 = 0; d0 < DHH; d0 += 32) {
    for (int i = tid; i < 67 * 32; i += 256) {
      int r = i >> 5, c = i & 31;
      int s = s0 - 3 + r;
      float v = 0.f;
      if (s >= 0) v = x[((size_t)b * SS + s) * EE + h * DHH + d0 + c];
      Xs[r][c] = v;
    }
    for (int i = tid; i < 32 * 64; i += 256) {
      int j = i >> 5, c = i & 31;
      int o = n0 + j;
      const float* Wp = (o < 256) ? W0 : W1;
      int oo = o & 255;
      Bs[c][j] = Wp[((size_t)h * DHH + oo) * DHH + d0 + c];
    }
    __syncthreads();
    if (pair == 0) {
      for (int i = tid; i < 64 * 32; i += 256) {
        int r = i >> 5, c = i & 31;
        int e = h * DHH + d0 + c;
        float xc = conv_b[e];
        xc = fmaf(Xs[r + 0][c], conv_w[0 * EE + e], xc);
        xc = fmaf(Xs[r + 1][c], conv_w[1 * EE + e], xc);
        xc = fmaf(Xs[r + 2][c], conv_w[2 * EE + e], xc);
        xc = fmaf(Xs[r + 3][c], conv_w[3 * EE + e], xc);
        float sg = 1.f / (1.f + __expf(-xc));
        As[r][c] = xc * sg;
      }
    } else {
      for (int i = tid; i < 64 * 32; i += 256) {
        int r = i >> 5, c = i & 31;
        As[r][c] = Xs[r + 3][c];
      }
    }
    __syncthreads();
#pragma unroll
    for (int kk = 0; kk < 32; ++kk) {
      float a[4];
#pragma unroll
      for (int i = 0; i < 4; ++i) a[i] = As[ty * 4 + i][kk];
      float4 bv = *(const float4*)&Bs[kk][tx * 4];
      float bb[4] = {bv.x, bv.y, bv.z, bv.w};
#pragma unroll
      for (int i = 0; i < 4; ++i)
#pragma unroll
        for (int j = 0; j < 4; ++j)
          acc[i][j] = fmaf(a[i], bb[j], acc[i][j]);
    }
    __syncthreads();
  }

#pragma unroll
  for (int i = 0; i < 4; ++i) {
    int s = s0 + ty * 4 + i;
    size_t base = (((size_t)s * BB + b) * NHH + h) * 1024 + (size_t)pair * 512 + n0 + tx * 4;
    uint2 st;
    st.x = h2u(__floats2half2_rn(acc[i][0], acc[i][1]));
    st.y = h2u(__floats2half2_rn(acc[i][2], acc[i][3]));
    *(uint2*)(gx + base) = st;
  }
}

// ---------------------------------------------------------------------------
// sLSTM scan, 2 CUs per chain. grid = 64 WGs x 1024 threads.
// Round-8 structure with the OOB publish fixed (l < 16 guards): ystage slot
// is 16 uint4; lanes 16..63 were clobbering neighboring ring slots and the
// yflag array -> deadlock.
//  - amdgpu_waves_per_eu(4,4): dynamic LDS hides 1-WG/CU from the register
//    allocator (it targeted 8 waves/EU -> 64 VGPRs -> weight spill).
//  - y-half publish by lanes 0..15 of wave 0 (1 dwordx4 each); lane-0
//    agent-release store orders the wave's prior stores.
//  - out-row flush by wave 1.
// ---------------------------------------------------------------------------
__global__ __attribute__((amdgpu_flat_work_group_size(1024, 1024),
                          amdgpu_waves_per_eu(4, 4)))
void slstm_scan2(
    const float* __restrict__ rk,    // (NH, DH, 4*DH)
    const float* __restrict__ rb,    // (NH, 4, DH)
    const __half* __restrict__ gx,   // [S][B][NH][1024]
    float* __restrict__ out,         // (B, S, E)
    __half* __restrict__ ybuf,       // [32][2][4][128] f16 ring
    int* __restrict__ yflag)         // [32][2][4] stamps (memset 0 per launch)
{
  extern __shared__ unsigned char smem2[];
  float* partial = (float*)smem2;                                // [2][1024]
  __half (*ystage)[128] = (__half(*)[128])(smem2 + 8192);        // [4][128]
  float (*ostage)[128] = (float(*)[128])(smem2 + 8192 + 1024);   // [4][128]

  const int t = threadIdx.x;
  const int w = t >> 6, l = t & 63;
  const int myhalf = blockIdx.x >> 5;
  const int c = blockIdx.x & 31;
  const int b = c >> 2, h = c & 3;
  const int p = w & 1;
  const int g = l & 3;
  const int d_loc = ((w >> 1) << 4) | (l >> 2);       // 0..127
  const int col = g * 256 + myhalf * 128 + d_loc;     // 0..1023
  const float* Rh = rk + (size_t)h * DHH * 1024;

  // 64 half2 weights: k in [p*128, p*128+128), register-resident
  unsigned int wv[64];
#pragma unroll
  for (int i = 0; i < 64; ++i) {
    int k = (p << 7) + 2 * i;
    wv[i] = pack2(Rh[(size_t)k * 1024 + col], Rh[(size_t)(k + 1) * 1024 + col]);
  }
  const float rbv = rb[h * 1024 + col];

  // prologue: zero y(0) staging + publish zero slot 0
  if (t < 128) {
#pragma unroll
    for (int s = 0; s < 4; ++s) ystage[s][t] = __float2half(0.f);
  }
  if (w == 0) {
    if (l < 16) {
      uint4 z; z.x = z.y = z.z = z.w = 0u;
      uint4* dst = (uint4*)(ybuf + (((size_t)c * 2 + myhalf) * 4 + 0) * 128);
      dst[l] = z;
    }
    if (l == 0)
      __hip_atomic_store(&yflag[(c * 2 + myhalf) * 4 + 0], 1,
                         __ATOMIC_RELEASE, __HIP_MEMORY_SCOPE_AGENT);
  }
  __syncthreads();

  float cst = 0.f, nst = 0.f, mst = 0.f;
  const size_t gxstep = (size_t)BB * NHH * 1024;
  const __half* gp = gx + ((size_t)b * NHH + h) * 1024 + col;

  for (int st = 0; st < SS; ++st) {
    const int slot = st & 3;
    const float cx = __half2float(gp[(size_t)st * gxstep]);

    // ---- matvec over this lane's k-half ----
    float dotsum = 0.f;
    if (p == myhalf) {
      const uint4* ys = (const uint4*)ystage[slot];
#pragma unroll
      for (int j = 0; j < 16; ++j) {
        uint4 yq = ys[j];
        dotsum = fdot2u(wv[4 * j + 0], yq.x, dotsum);
        dotsum = fdot2u(wv[4 * j + 1], yq.y, dotsum);
        dotsum = fdot2u(wv[4 * j + 2], yq.z, dotsum);
        dotsum = fdot2u(wv[4 * j + 3], yq.w, dotsum);
      }
    } else {
      const int fidx = (c * 2 + p) * 4 + slot;
      const int want = st + 1;
      while (__hip_atomic_load(&yflag[fidx], __ATOMIC_ACQUIRE,
                               __HIP_MEMORY_SCOPE_AGENT) < want) {
        __builtin_amdgcn_s_sleep(2);
      }
      const uint4* ys = (const uint4*)(ybuf + (((size_t)c * 2 + p) * 4 + slot) * 128);
#pragma unroll
      for (int j = 0; j < 16; ++j) {
        uint4 yq = ys[j];
        dotsum = fdot2u(wv[4 * j + 0], yq.x, dotsum);
        dotsum = fdot2u(wv[4 * j + 1], yq.y, dotsum);
        dotsum = fdot2u(wv[4 * j + 2], yq.z, dotsum);
        dotsum = fdot2u(wv[4 * j + 3], yq.w, dotsum);
      }
    }

    // ---- combine k-halves across wave pair (w <-> w^1) via LDS ----
    float* pb = partial + (st & 1) * 1024;
    pb[t] = dotsum;
    __syncthreads();                       // b1
    float sum2 = dotsum + pb[t ^ 64];
    float v0 = sum2 + cx + rbv;            // complete raw gate g

    // ---- gather all 4 gates within the 4-lane group ----
    float x1 = __shfl_xor(v0, 1);
    float x2 = __shfl_xor(v0, 2);
    float x3 = __shfl_xor(x1, 2);
    float iv = (g == 0) ? v0 : (g == 1) ? x1 : (g == 2) ? x2 : x3;
    float fv = (g == 0) ? x1 : (g == 1) ? v0 : (g == 2) ? x3 : x2;
    float zv = (g == 0) ? x2 : (g == 1) ? x3 : (g == 2) ? v0 : x1;
    float ov = (g == 0) ? x3 : (g == 1) ? x2 : (g == 2) ? x1 : v0;

    // ---- state update (redundant across the 8 lanes of a dim) ----
    float ea = __expf(-fabsf(fv));
    float ls = fminf(fv, 0.f) - __logf(1.f + ea);      // log_sigmoid(fv)
    float lfm = mst + ls;
    float mn = fmaxf(iv, lfm);
    float ig = __expf(iv - mn);
    float fg = __expf(lfm - mn);
    float pz = __expf(-2.f * fabsf(zv));
    float tmag = __fdividef(1.f - pz, 1.f + pz);
    float th = (zv < 0.f) ? -tmag : tmag;              // tanh(zv)
    cst = fg * cst + ig * th;
    nst = fg * nst + ig;
    float og = __fdividef(1.f, 1.f + __expf(-ov));     // sigmoid(ov)
    float y = og * __fdividef(cst, nst);
    mst = mn;

    // ---- stage y(st+1) and out row ----
    if (((w & 1) == 0) && g == 0) {
      ystage[(st + 1) & 3][d_loc] = __float2half(y);
      ostage[slot][d_loc] = y;
    }
    __syncthreads();                       // b2

    // publish own y-half for peer: lanes 0..15 of wave 0, one dwordx4 each
    if (w == 0 && st + 1 < SS) {
      const int ps = (st + 1) & 3;
      if (l < 16) {
        uint4* dst = (uint4*)(ybuf + (((size_t)c * 2 + myhalf) * 4 + ps) * 128);
        const uint4* src = (const uint4*)ystage[ps];
        dst[l] = src[l];
      }
      if (l == 0)
        __hip_atomic_store(&yflag[(c * 2 + myhalf) * 4 + ps], st + 2,
                           __ATOMIC_RELEASE, __HIP_MEMORY_SCOPE_AGENT);
    }
    // flush out row (coalesced 512 B), wave 1
    if (w == 1 && l < 32) {
      float4 v = *(const float4*)&ostage[slot][l * 4];
      *(float4*)&out[((size_t)b * SS + st) * EE + h * DHH + myhalf * 128 + l * 4] = v;
    }
  }
}

// ---------------------------------------------------------------------------
// GroupNorm over DH per (b,s,h), in place on out. One wave = one head.
// ---------------------------------------------------------------------------
__global__ __launch_bounds__(256) void groupnorm(
    float* __restrict__ y, const float* __restrict__ gnw)
{
  const int row = blockIdx.x;
  const int t = threadIdx.x;
  float4 v = ((const float4*)y)[(size_t)row * 256 + t];
  float s = v.x + v.y + v.z + v.w;
  float q = v.x * v.x + v.y * v.y + v.z * v.z + v.w * v.w;
#pragma unroll
  for (int mask = 1; mask < 64; mask <<= 1) {
    s += __shfl_xor(s, mask, 64);
    q += __shfl_xor(q, mask, 64);
  }
  float mu = s * (1.f / 256.f);
  float var = q * (1.f / 256.f) - mu * mu;
  float rs = rsqrtf(var + 1e-5f);
  float4 g = ((const float4*)gnw)[t];
  float4 o;
  o.x = (v.x - mu) * rs * g.x;
  o.y = (v.y - mu) * rs * g.y;
  o.z = (v.z - mu) * rs * g.z;
  o.w = (v.w - mu) * rs * g.w;
  ((float4*)y)[(size_t)row * 256 + t] = o;
}

extern "C" void kernel_launch(void* const* d_in, const int* in_sizes, int n_in,
                              void* d_out, int out_size, void* d_ws, size_t ws_size,
                              hipStream_t stream) {
  const float* x      = (const float*)d_in[0];
  const float* conv_w = (const float*)d_in[1];
  const float* conv_b = (const float*)d_in[2];
  const float* fgw    = (const float*)d_in[3];
  const float* igw    = (const float*)d_in[4];
  const float* zgw    = (const float*)d_in[5];
  const float* ogw    = (const float*)d_in[6];
  const float* rk     = (const float*)d_in[7];
  const float* rb     = (const float*)d_in[8];
  const float* gnw    = (const float*)d_in[9];
  float* out = (float*)d_out;

  __half* gx   = (__half*)d_ws;                              // 134217728 B
  __half* ybuf = (__half*)((char*)d_ws + 134217728);         // 65536 B
  int*   yflag = (int*)((char*)d_ws + 134217728 + 65536);    // 1024 B

  (void)hipMemsetAsync(yflag, 0, 1024, stream);

  dim3 g1(256, 8, 8);
  gates_gemm<<<g1, 256, 0, stream>>>(x, conv_w, conv_b, fgw, igw, zgw, ogw, gx);

  const int scan_lds = 98304;   // force 1 WG/CU
  (void)hipFuncSetAttribute(reinterpret_cast<const void*>(slstm_scan2),
                            hipFuncAttributeMaxDynamicSharedMemorySize, scan_lds);
  slstm_scan2<<<64, 1024, scan_lds, stream>>>(rk, rb, gx, out, ybuf, yflag);

  groupnorm<<<BB * SS, 256, 0, stream>>>(out, gnw);
}

// Round 10
// 3958.119 us; speedup vs baseline: 5.8197x; 4.5355x over previous
//
#include <hip/hip_runtime.h>
#include <hip/hip_fp16.h>

#define BB 8
#define SS 2048
#define EE 1024
#define NHH 4
#define DHH 256

typedef _Float16 f16x2 __attribute__((ext_vector_type(2)));
typedef _Float16 f16x8 __attribute__((ext_vector_type(8)));
typedef float f32x4 __attribute__((ext_vector_type(4)));

__device__ __forceinline__ __half2 u2h2(unsigned int u) {
  union { unsigned int u; __half2 h; } c; c.u = u; return c.h;
}
__device__ __forceinline__ unsigned int h2u(__half2 h) {
  union { unsigned int u; __half2 h; } c; c.h = h; return c.u;
}
__device__ __forceinline__ f16x2 u2f(unsigned int u) {
  union { unsigned int u; f16x2 f; } c; c.u = u; return c.f;
}
__device__ __forceinline__ unsigned int pack2(float a, float b) {
  f16x2 f; f.x = (_Float16)a; f.y = (_Float16)b;
  union { f16x2 f; unsigned int u; } c; c.f = f; return c.u;
}
__device__ __forceinline__ float fdot2u(unsigned int w, unsigned int y, float acc) {
#if __has_builtin(__builtin_amdgcn_fdot2)
  return __builtin_amdgcn_fdot2(u2f(w), u2f(y), acc, false);
#else
  __half2 a = u2h2(w), b = u2h2(y);
  return acc + __low2float(a) * __low2float(b) + __high2float(a) * __high2float(b);
#endif
}

// ---------------------------------------------------------------------------
// Gates projection GEMM via MFMA f16 (fp32 accumulate).
// grid (256 m-tiles of 8 s-rows, 8 n-tiles, 8 problems), block 256 (4 waves).
// problem p: h = p>>1, pair = p&1. pair0: A = silu(conv(x)), W = [fgate;igate]
//                                  pair1: A = x,             W = [zgate;ogate]
// Output: gx f16, layout [S][B][NH][4*DH] = [i f z o]
// Tile: M=64 (8 s x 8 b), N=64, K=256 in 8 steps of 32.
// MFMA 16x16x32_f16: A lane(row=l&15, k=(l>>4)*8+i); B lane(col=l&15, same k);
// C/D col=lane&15, row=(lane>>4)*4+reg.
// ---------------------------------------------------------------------------
__global__ __launch_bounds__(256) void gates_gemm(
    const float* __restrict__ x, const float* __restrict__ conv_w,
    const float* __restrict__ conv_b,
    const float* __restrict__ fgw, const float* __restrict__ igw,
    const float* __restrict__ zgw, const float* __restrict__ ogw,
    __half* __restrict__ gx)
{
  __shared__ float Xs[8][11][33];     // pair0 conv staging: [b][si][kk]
  __shared__ __half As[64][40];       // A tile f16, padded
  __shared__ __half Bs[64][40];       // B tile f16, col-major [col][k]

  const int tid = threadIdx.x;
  const int mt = blockIdx.x;           // 0..255 -> s0 = mt*8
  const int nt = blockIdx.y;           // 0..7
  const int p  = blockIdx.z;           // 0..7
  const int h  = p >> 1, pair = p & 1;
  const int s0 = mt << 3;
  const int n0 = nt << 6;

  const float* W0 = pair ? zgw : fgw;  // output cols [0,256)
  const float* W1 = pair ? ogw : igw;  // output cols [256,512)

  const int w = tid >> 6, l = tid & 63;
  const int lrow = l & 15, kq = l >> 4;      // kq 0..3
  const int koff = kq << 3;

  f32x4 acc[4] = {};

  for (int d0 = 0; d0 < DHH; d0 += 32) {
    const int ebase = h * DHH + d0;

    if (pair == 0) {
      // stage x halo rows: 8 b x 11 si x 32 kk
      for (int i = tid; i < 8 * 11 * 32; i += 256) {
        int kk = i & 31, rest = i >> 5;        // rest 0..87
        int b = rest / 11, si = rest - b * 11;
        int sg = s0 - 3 + si;
        float v = 0.f;
        if (sg >= 0) v = x[((size_t)b * SS + sg) * EE + ebase + kk];
        Xs[b][si][kk] = v;
      }
      __syncthreads();
      // conv + silu -> As
      for (int i = tid; i < 64 * 32; i += 256) {
        int kk = i & 31, r = i >> 5;
        int sl = r >> 3, b = r & 7;
        int e = ebase + kk;
        float xc = conv_b[e];
        xc = fmaf(Xs[b][sl + 0][kk], conv_w[0 * EE + e], xc);
        xc = fmaf(Xs[b][sl + 1][kk], conv_w[1 * EE + e], xc);
        xc = fmaf(Xs[b][sl + 2][kk], conv_w[2 * EE + e], xc);
        xc = fmaf(Xs[b][sl + 3][kk], conv_w[3 * EE + e], xc);
        float sg = 1.f / (1.f + __expf(-xc));
        As[r][kk] = __float2half(xc * sg);
      }
    } else {
      // direct cast of x -> As
      for (int i = tid; i < 64 * 32; i += 256) {
        int kk = i & 31, r = i >> 5;
        int sl = r >> 3, b = r & 7;
        As[r][kk] = __float2half(x[((size_t)b * SS + s0 + sl) * EE + ebase + kk]);
      }
    }
    // stage B: Bs[col][k] = W[n0+col][d0+k]
    for (int i = tid; i < 64 * 32; i += 256) {
      int k = i & 31, col = i >> 5;
      int o = n0 + col;
      const float* Wp = (o < 256) ? W0 : W1;
      int oo = o & 255;
      Bs[col][k] = __float2half(Wp[((size_t)h * DHH + oo) * DHH + d0 + k]);
    }
    __syncthreads();

    // MFMA: wave w covers cols [n0 + w*16, +16); 4 M-tiles
    f16x8 bfrag = *(const f16x8*)&Bs[w * 16 + lrow][koff];
#pragma unroll
    for (int mtl = 0; mtl < 4; ++mtl) {
      f16x8 afrag = *(const f16x8*)&As[mtl * 16 + lrow][koff];
      acc[mtl] = __builtin_amdgcn_mfma_f32_16x16x32_f16(afrag, bfrag, acc[mtl], 0, 0, 0);
    }
    __syncthreads();
  }

  // epilogue: C/D col=lane&15, row=(lane>>4)*4+reg
#pragma unroll
  for (int mtl = 0; mtl < 4; ++mtl) {
#pragma unroll
    for (int j = 0; j < 4; ++j) {
      int row_loc = mtl * 16 + kq * 4 + j;
      int grow = s0 * 8 + row_loc;          // = s*8 + b
      int colg = n0 + w * 16 + lrow;
      gx[(size_t)grow * 4096 + h * 1024 + pair * 512 + colg] = __float2half(acc[mtl][j]);
    }
  }
}

// ---------------------------------------------------------------------------
// sLSTM scan (round-6 verbatim): one workgroup (512 threads) per chain (b,h).
// Lane-pair k-split: lane 2d owns dim d with k in [0,128); lane 2d+1 owns
// dim d with k in [128,256). Each lane computes partial sums of ALL FOUR
// gate columns (i,f,z,o at dim d) over its k-half via v_dot2_f32_f16;
// the pair combines partials with 4 shfl_xor(1) (in-wave, no barrier).
// Weights per lane: gates i,f,z (3 x 64 half2) in registers; gate o
// (64 half2) in LDS as uint4 [16][512]. y double-buffered in LDS f16;
// each lane reads only its k-half (16 x b128, two addrs per wave).
// One barrier per step.
// Dynamic LDS: 131072 (wl4) + 1024 (ypub x2) = 132096 B
// ---------------------------------------------------------------------------
__global__
__attribute__((amdgpu_flat_work_group_size(512, 512), amdgpu_waves_per_eu(1)))
void slstm_scan(
    const float* __restrict__ rk,    // (NH, DH, 4*DH)
    const float* __restrict__ rb,    // (NH, 4, DH)
    const __half* __restrict__ gx,   // [S][B][NH][1024]
    float* __restrict__ out)         // (B, S, E)
{
  extern __shared__ unsigned char smem[];
  uint4* wl4   = (uint4*)smem;                      // [16][512]
  __half* ypub = (__half*)(smem + 131072);          // [2][256]

  const int t = threadIdx.x;
  const int b = blockIdx.x >> 2, h = blockIdx.x & 3;
  const int d = t >> 1, par = t & 1;
  const int kbase = par << 7;                       // 0 or 128
  const float* Rh = rk + (size_t)h * DHH * 1024;

  // weights: gates 0..2 (i,f,z) in registers, gate 3 (o) in LDS
  unsigned int wv[3][64];
#pragma unroll
  for (int g = 0; g < 3; ++g) {
    const int col = g * 256 + d;
#pragma unroll
    for (int pp = 0; pp < 64; ++pp) {
      int k = kbase + 2 * pp;
      wv[g][pp] = pack2(Rh[(size_t)k * 1024 + col], Rh[(size_t)(k + 1) * 1024 + col]);
    }
  }
  {
    const int col = 3 * 256 + d;
    for (int q = 0; q < 16; ++q) {
      uint4 u;
      int k = kbase + 8 * q;
      u.x = pack2(Rh[(size_t)(k + 0) * 1024 + col], Rh[(size_t)(k + 1) * 1024 + col]);
      u.y = pack2(Rh[(size_t)(k + 2) * 1024 + col], Rh[(size_t)(k + 3) * 1024 + col]);
      u.z = pack2(Rh[(size_t)(k + 4) * 1024 + col], Rh[(size_t)(k + 5) * 1024 + col]);
      u.w = pack2(Rh[(size_t)(k + 6) * 1024 + col], Rh[(size_t)(k + 7) * 1024 + col]);
      wl4[q * 512 + t] = u;
    }
  }

  float rbv[4];
#pragma unroll
  for (int g = 0; g < 4; ++g) rbv[g] = rb[h * 1024 + g * 256 + d];

  float c = 0.f, n = 0.f, m = 0.f;
  if (t < 256) { ypub[t] = __float2half(0.f); ypub[256 + t] = __float2half(0.f); }
  __syncthreads();

  int cur = 0;
  const __half* pg = gx + ((size_t)b * NHH + h) * 1024;
  float cx[4];
#pragma unroll
  for (int g = 0; g < 4; ++g) cx[g] = __half2float(pg[g * 256 + d]);
  const size_t out_base = ((size_t)b * SS) * EE + h * DHH + d;

  for (int st = 0; st < SS; ++st) {
    // prefetch next step's gate inputs
    const __half* pn = pg + ((st + 1 < SS) ? (size_t)(BB * NHH * 1024) : 0);
    __half nx[4];
#pragma unroll
    for (int g = 0; g < 4; ++g) nx[g] = pn[g * 256 + d];

    const uint4* yv = (const uint4*)(ypub + cur * 256) + (par << 4);
    float aA0 = 0.f, aB0 = 0.f, aA1 = 0.f, aB1 = 0.f;
    float aA2 = 0.f, aB2 = 0.f, aA3 = 0.f, aB3 = 0.f;
#pragma unroll
    for (int j = 0; j < 16; ++j) {
      uint4 yq = yv[j];                 // y dims kbase+8j .. kbase+8j+7
      uint4 wq = wl4[j * 512 + t];      // gate-3 weights, same k-range
      aA0 = fdot2u(wv[0][4 * j + 0], yq.x, aA0);
      aA1 = fdot2u(wv[1][4 * j + 0], yq.x, aA1);
      aA2 = fdot2u(wv[2][4 * j + 0], yq.x, aA2);
      aA3 = fdot2u(wq.x,             yq.x, aA3);
      aB0 = fdot2u(wv[0][4 * j + 1], yq.y, aB0);
      aB1 = fdot2u(wv[1][4 * j + 1], yq.y, aB1);
      aB2 = fdot2u(wv[2][4 * j + 1], yq.y, aB2);
      aB3 = fdot2u(wq.y,             yq.y, aB3);
      aA0 = fdot2u(wv[0][4 * j + 2], yq.z, aA0);
      aA1 = fdot2u(wv[1][4 * j + 2], yq.z, aA1);
      aA2 = fdot2u(wv[2][4 * j + 2], yq.z, aA2);
      aA3 = fdot2u(wq.z,             yq.z, aA3);
      aB0 = fdot2u(wv[0][4 * j + 3], yq.w, aB0);
      aB1 = fdot2u(wv[1][4 * j + 3], yq.w, aB1);
      aB2 = fdot2u(wv[2][4 * j + 3], yq.w, aB2);
      aB3 = fdot2u(wq.w,             yq.w, aB3);
    }

    // combine k-halves across the lane pair (even<->odd), all 4 gates
    float part0 = aA0 + aB0, part1 = aA1 + aB1;
    float part2 = aA2 + aB2, part3 = aA3 + aB3;
    float raw0 = part0 + __shfl_xor(part0, 1) + cx[0] + rbv[0];
    float raw1 = part1 + __shfl_xor(part1, 1) + cx[1] + rbv[1];
    float raw2 = part2 + __shfl_xor(part2, 1) + cx[2] + rbv[2];
    float raw3 = part3 + __shfl_xor(part3, 1) + cx[3] + rbv[3];

    // state update (redundant in both lanes of the pair)
    float iv = raw0, fv = raw1, zv = raw2, ov = raw3;
    float ea = __expf(-fabsf(fv));
    float ls = fminf(fv, 0.f) - __logf(1.f + ea);      // log_sigmoid(fv)
    float lfm = m + ls;
    float mn = fmaxf(iv, lfm);
    float ig = __expf(iv - mn);
    float fg = __expf(lfm - mn);
    float pz = __expf(-2.f * fabsf(zv));
    float tmag = __fdividef(1.f - pz, 1.f + pz);
    float th = (zv < 0.f) ? -tmag : tmag;              // tanh(zv)
    c = fg * c + ig * th;
    n = fg * n + ig;
    float og = __fdividef(1.f, 1.f + __expf(-ov));     // sigmoid(ov)
    float y = og * __fdividef(c, n);
    m = mn;

    if (par == 0) {
      out[out_base + (size_t)st * EE] = y;
      ypub[(cur ^ 1) * 256 + d] = __float2half(y);
    }
    __syncthreads();
    cur ^= 1;
    pg = pn;
#pragma unroll
    for (int g = 0; g < 4; ++g) cx[g] = __half2float(nx[g]);
  }
}

// ---------------------------------------------------------------------------
// GroupNorm over DH per (b,s,h), in place on out. One wave = one head.
// ---------------------------------------------------------------------------
__global__ __launch_bounds__(256) void groupnorm(
    float* __restrict__ y, const float* __restrict__ gnw)
{
  const int row = blockIdx.x;
  const int t = threadIdx.x;
  float4 v = ((const float4*)y)[(size_t)row * 256 + t];
  float s = v.x + v.y + v.z + v.w;
  float q = v.x * v.x + v.y * v.y + v.z * v.z + v.w * v.w;
#pragma unroll
  for (int mask = 1; mask < 64; mask <<= 1) {
    s += __shfl_xor(s, mask, 64);
    q += __shfl_xor(q, mask, 64);
  }
  float mu = s * (1.f / 256.f);
  float var = q * (1.f / 256.f) - mu * mu;
  float rs = rsqrtf(var + 1e-5f);
  float4 g = ((const float4*)gnw)[t];
  float4 o;
  o.x = (v.x - mu) * rs * g.x;
  o.y = (v.y - mu) * rs * g.y;
  o.z = (v.z - mu) * rs * g.z;
  o.w = (v.w - mu) * rs * g.w;
  ((float4*)y)[(size_t)row * 256 + t] = o;
}

extern "C" void kernel_launch(void* const* d_in, const int* in_sizes, int n_in,
                              void* d_out, int out_size, void* d_ws, size_t ws_size,
                              hipStream_t stream) {
  const float* x      = (const float*)d_in[0];
  const float* conv_w = (const float*)d_in[1];
  const float* conv_b = (const float*)d_in[2];
  const float* fgw    = (const float*)d_in[3];
  const float* igw    = (const float*)d_in[4];
  const float* zgw    = (const float*)d_in[5];
  const float* ogw    = (const float*)d_in[6];
  const float* rk     = (const float*)d_in[7];
  const float* rb     = (const float*)d_in[8];
  const float* gnw    = (const float*)d_in[9];
  float* out = (float*)d_out;
  __half* gx = (__half*)d_ws;   // [S][B][NH][1024] f16 = 134217728 B

  dim3 g1(256, 8, 8);
  gates_gemm<<<g1, 256, 0, stream>>>(x, conv_w, conv_b, fgw, igw, zgw, ogw, gx);

  const int scan_lds = 131072 + 1024;
  (void)hipFuncSetAttribute(reinterpret_cast<const void*>(slstm_scan),
                            hipFuncAttributeMaxDynamicSharedMemorySize, scan_lds);
  slstm_scan<<<32, 512, scan_lds, stream>>>(rk, rb, gx, out);

  groupnorm<<<BB * SS, 256, 0, stream>>>(out, gnw);
}